// Round 2
// baseline (1195.114 us; speedup 1.0000x reference)
//
#include <hip/hip_runtime.h>
#include <cmath>

#define HD 512      // hidden
#define IN 512      // input features (K)
#define TT 784      // timesteps
#define BB 128      // batch
#define MH 50176    // rows per batch-half (64 * 784)

typedef short short8 __attribute__((ext_vector_type(8)));
typedef unsigned short ushort8 __attribute__((ext_vector_type(8)));
typedef float floatx4 __attribute__((ext_vector_type(4)));

#define GLDS(gp, lp) __builtin_amdgcn_global_load_lds( \
    (const __attribute__((address_space(1))) void*)(gp), \
    (__attribute__((address_space(3))) void*)(lp), 16, 0, 0)

__device__ __forceinline__ unsigned short bf16_rne(float x) {
    unsigned u = __float_as_uint(x);
    unsigned r = u + 0x7FFFu + ((u >> 16) & 1u);
    return (unsigned short)(r >> 16);
}
__device__ __forceinline__ float bf16_f(unsigned short s) {
    return __uint_as_float(((unsigned)s) << 16);
}

// ---------------- split fp32 -> 3 bf16 planes (exact residual chain) --------
__global__ __launch_bounds__(256) void split3(
    const float* __restrict__ src, unsigned short* __restrict__ p1,
    unsigned short* __restrict__ p2, unsigned short* __restrict__ p3, long n8)
{
    long g = (long)blockIdx.x * 256 + threadIdx.x;
    if (g >= n8) return;
    const float* xp = src + g * 8;
    ushort8 o1, o2, o3;
#pragma unroll
    for (int j = 0; j < 8; ++j) {
        float x = xp[j];
        unsigned short s1 = bf16_rne(x);
        float r1 = x - bf16_f(s1);                 // exact in fp32
        unsigned short s2 = bf16_rne(r1);
        float r2 = r1 - bf16_f(s2);                // exact in fp32
        unsigned short s3 = bf16_rne(r2);
        o1[j] = s1; o2[j] = s2; o3[j] = s3;
    }
    *(ushort8*)(p1 + g * 8) = o1;
    *(ushort8*)(p2 + g * 8) = o2;
    *(ushort8*)(p3 + g * 8) = o3;
}

// ---------------- MFMA GEMM (bf16x3), pipelined schedule --------------------
// d = X*W^T + bias;  X*W ~= a1b1 + (a1b2+a2b1) + (a1b3+a2b2+a3b1), fp32 accum.
// 256x128 tile, 8 waves (4M x 2N), per-wave 64x64, 16x16x32 MFMA, BK=32.
// Double-buffered 144 KB dynamic LDS; counted vmcnt(9) (2-deep prefetch);
// XOR 16B-slot swizzle (pre-swizzled global src, swizzled read); setprio(1)
// around MFMA clusters; XCD-chunked block swizzle (A-panel locality).
__global__ __launch_bounds__(512, 2) void gemm_bf16x3_p(
    const unsigned short* __restrict__ Xp,   // [3][MH][512]
    const unsigned short* __restrict__ Wp,   // [3][1024][512]
    const float* __restrict__ b1, const float* __restrict__ b2,
    float* __restrict__ d1buf, float* __restrict__ d2buf)
{
    extern __shared__ unsigned short lds[];   // 2 x 36864 ushorts (144 KB)
    const int tid  = threadIdx.x;
    const int lane = tid & 63;
    const int w    = tid >> 6;

    // XCD-chunked swizzle: 1568 blocks = 8 chunks x 196; within a chunk,
    // consecutive wg share the same 256-row A panel (pn fast) -> L2 locality.
    const int wg = (blockIdx.x & 7) * 196 + (blockIdx.x >> 3);
    const int pm = wg >> 3;             // 0..195
    const int pn = wg & 7;              // 0..7 over N=1024
    const int m0 = pm * 256;
    const int n0 = pn * 128;

    // ---- staging: 72 segments of 1 KB (16 rows x 32 cols), 9 per wave.
    // GLDS writes seg_base + lane*16B (linear). Source col is pre-swizzled:
    // 16B slot s_phys=lane&3 holds logical slot (lane&3)^f(row),
    // f(row) = (row&3) ^ ((row>>2)&3); row_in_seg = lane>>2.
    const unsigned short* gp[9];
    unsigned loff[9];
    {
        const int rsub = lane >> 2;                       // 0..15
        const int fst  = ((lane >> 2) & 3) ^ ((lane >> 4) & 3);
        const int csub = (((lane & 3) ^ fst) * 8);        // ushort offset
#pragma unroll
        for (int j = 0; j < 9; ++j) {
            int s = w * 9 + j;                            // 0..71
            const unsigned short* src;
            if (s < 48) {                                 // A: plane p, rb
                int p = s >> 4, rb = s & 15;
                src = Xp + ((size_t)p * MH + m0 + rb * 16 + rsub) * IN + csub;
            } else {                                      // B
                int t2 = s - 48;
                int p = t2 >> 3, rb = t2 & 7;
                src = Wp + ((size_t)p * 1024 + n0 + rb * 16 + rsub) * IN + csub;
            }
            gp[j] = src;
            loff[j] = (unsigned)s * 512;                  // ushort offset
        }
    }

    floatx4 acc[4][4];
#pragma unroll
    for (int i = 0; i < 4; ++i)
#pragma unroll
        for (int j = 0; j < 4; ++j) acc[i][j] = (floatx4){0.f, 0.f, 0.f, 0.f};

    const int wm = w >> 1, wn = w & 1;                    // 4 x 2 waves
    const int c16 = lane & 15;
    // read-side swizzle: slot' = (lane>>4) ^ f(row), f depends only on c16
    const int fr   = (lane & 3) ^ ((lane >> 2) & 3);
    const int q8s  = (((lane >> 4) ^ fr) & 3) * 8;

    auto compute = [&](int cb) {
        short8 Bf[3][4];
#pragma unroll
        for (int p = 0; p < 3; ++p)
#pragma unroll
            for (int fj = 0; fj < 4; ++fj)
                Bf[p][fj] = *(const short8*)&lds[cb + 24576 + p * 4096 +
                    (wn * 64 + fj * 16 + c16) * 32 + q8s];
#pragma unroll
        for (int fi = 0; fi < 4; ++fi) {
            const int ra = cb + (wm * 64 + fi * 16 + c16) * 32 + q8s;
            short8 a1 = *(const short8*)&lds[ra];
            short8 a2 = *(const short8*)&lds[ra + 8192];
            short8 a3 = *(const short8*)&lds[ra + 16384];
            __builtin_amdgcn_s_setprio(1);
#pragma unroll
            for (int fj = 0; fj < 4; ++fj) {
                floatx4 c = acc[fi][fj];
                c = __builtin_amdgcn_mfma_f32_16x16x32_bf16(a3, Bf[0][fj], c, 0, 0, 0);
                c = __builtin_amdgcn_mfma_f32_16x16x32_bf16(a2, Bf[1][fj], c, 0, 0, 0);
                c = __builtin_amdgcn_mfma_f32_16x16x32_bf16(a1, Bf[2][fj], c, 0, 0, 0);
                c = __builtin_amdgcn_mfma_f32_16x16x32_bf16(a2, Bf[0][fj], c, 0, 0, 0);
                c = __builtin_amdgcn_mfma_f32_16x16x32_bf16(a1, Bf[1][fj], c, 0, 0, 0);
                c = __builtin_amdgcn_mfma_f32_16x16x32_bf16(a1, Bf[0][fj], c, 0, 0, 0);
                acc[fi][fj] = c;
            }
            __builtin_amdgcn_s_setprio(0);
        }
    };

    // prologue: stage k-steps 0 and 1 (9 GLDS each -> 18 in flight)
#pragma unroll
    for (int j = 0; j < 9; ++j) GLDS(gp[j],      lds + loff[j]);
#pragma unroll
    for (int j = 0; j < 9; ++j) GLDS(gp[j] + 32, lds + 36864 + loff[j]);

#pragma unroll 1
    for (int t = 0; t < 15; ++t) {
        asm volatile("s_waitcnt vmcnt(9)" ::: "memory");  // oldest 9 (step t) done
        __builtin_amdgcn_s_barrier();                      // all waves staged buf
        const int cb = (t & 1) * 36864;
        compute(cb);
        __builtin_amdgcn_s_barrier();                      // all waves done reading
        if (t < 14) {                                      // refill with step t+2
            const int ks = (t + 2) * 32;
#pragma unroll
            for (int j = 0; j < 9; ++j) GLDS(gp[j] + ks, lds + cb + loff[j]);
        }
    }
    asm volatile("s_waitcnt vmcnt(0)" ::: "memory");
    __builtin_amdgcn_s_barrier();
    compute(36864);                                        // step 15 -> buf1

    // epilogue: C layout col=lane&15, row=(lane>>4)*4+reg (m89-verified)
    const int quad = lane >> 4;
    const bool first = (n0 < HD);
    const float* bias = first ? b1 : b2;
    float* obuf = first ? d1buf : d2buf;
    const int nb = n0 & (HD - 1);
    float bv[4];
#pragma unroll
    for (int fj = 0; fj < 4; ++fj) bv[fj] = bias[nb + wn * 64 + fj * 16 + c16];
#pragma unroll
    for (int fi = 0; fi < 4; ++fi) {
#pragma unroll
        for (int fj = 0; fj < 4; ++fj) {
            int n = nb + wn * 64 + fj * 16 + c16;
#pragma unroll
            for (int r = 0; r < 4; ++r) {
                int m = m0 + wm * 64 + fi * 16 + quad * 4 + r;
                obuf[(size_t)m * HD + n] = acc[fi][fj][r] + bv[fj];
            }
        }
    }
}

// ---------------- Scan: full T per (b,h), one batch-half per dispatch -------
__global__ __launch_bounds__(64) void scan_half(
    const float* __restrict__ d1buf, const float* __restrict__ d2buf,
    const float* __restrict__ tau_m, const float* __restrict__ tau_n1,
    const float* __restrict__ tau_n2,
    const float* __restrict__ mem0, const float* __restrict__ spike0,
    unsigned short* __restrict__ spikes, int b0)
{
    const int gid = blockIdx.x * 64 + threadIdx.x;   // 0..32767
    const int h  = gid & (HD - 1);
    const int bl = gid >> 9;                          // local batch 0..63
    const int b  = b0 + bl;
    const float alpha = 1.f / (1.f + expf(-tau_m[h]));
    const float be1   = 1.f / (1.f + expf(-tau_n1[h]));
    const float be2   = 1.f / (1.f + expf(-tau_n2[h]));
    float mem = mem0[b * HD + h];
    float spk = spike0[b * HD + h];
    float d1 = 0.f, d2 = 0.f;
    const float* p1 = d1buf + (size_t)bl * TT * HD + h;
    const float* p2 = d2buf + (size_t)bl * TT * HD + h;
    unsigned short* sp = spikes + (size_t)b * (TT / 16) * HD + h;

#pragma unroll 1
    for (int g = 0; g < TT / 16; ++g) {
        float a1[16], a2[16];
#pragma unroll
        for (int i = 0; i < 16; ++i) {
            a1[i] = p1[(size_t)(g * 16 + i) * HD];
            a2[i] = p2[(size_t)(g * 16 + i) * HD];
        }
        unsigned int word = 0;
#pragma unroll
        for (int i = 0; i < 16; ++i) {
            d1 = be1 * d1 + (1.f - be1) * a1[i];
            d2 = be2 * d2 + (1.f - be2) * a2[i];
            float total = d1 + d2;
            mem = mem * alpha + (1.f - alpha) * total - spk;
            bool fire = (mem - 1.0f) > 0.f;
            spk = fire ? 1.f : 0.f;
            word |= (fire ? 1u : 0u) << i;
        }
        sp[(size_t)g * HD] = (unsigned short)word;
    }
}

// ---------------- Readout (round-1/4 validated) -----------------------------
__global__ __launch_bounds__(256) void readout(
    const unsigned short* __restrict__ spikes,
    const float* __restrict__ Wr, const float* __restrict__ br,
    float* __restrict__ out)
{
    __shared__ float WrS[10 * HD];   // 20 KB, layout [o][h]
    __shared__ float brS[10];
    const int tid = threadIdx.x;
    for (int i = tid; i < 10 * HD; i += 256) WrS[i] = Wr[i];
    if (tid < 10) brS[tid] = br[tid];
    __syncthreads();

    const int gid = blockIdx.x * 256 + tid;      // 0..100351 = b*784+t
    const int t = gid % TT;
    const int b = gid / TT;
    const int tw  = t >> 4;
    const int bit = t & 15;
    const unsigned short* row = spikes + ((size_t)b * (TT / 16) + tw) * HD;

    float acc[10];
#pragma unroll
    for (int o = 0; o < 10; ++o) acc[o] = brS[o];

    for (int h = 0; h < HD; ++h) {
        float s = (float)((row[h] >> bit) & 1);
#pragma unroll
        for (int o = 0; o < 10; ++o) acc[o] = fmaf(s, WrS[o * HD + h], acc[o]);
    }
    float* op = out + (size_t)gid * 10;
#pragma unroll
    for (int o = 0; o < 10; ++o) op[o] = acc[o];
}

// ---------------------------------------------------------------------------
extern "C" void kernel_launch(void* const* d_in, const int* in_sizes, int n_in,
                              void* d_out, int out_size, void* d_ws, size_t ws_size,
                              hipStream_t stream)
{
    const float* X      = (const float*)d_in[0];
    const float* W1     = (const float*)d_in[1];
    const float* b1     = (const float*)d_in[2];
    const float* W2     = (const float*)d_in[3];
    const float* b2     = (const float*)d_in[4];
    const float* tau_m  = (const float*)d_in[5];
    const float* tau_n1 = (const float*)d_in[6];
    const float* tau_n2 = (const float*)d_in[7];
    const float* Wr     = (const float*)d_in[8];
    const float* br     = (const float*)d_in[9];
    const float* mem0   = (const float*)d_in[10];
    const float* spike0 = (const float*)d_in[11];
    float* out = (float*)d_out;

    // one-time: allow 144 KB dynamic LDS for the GEMM
    static int s_attr = 0;
    if (!s_attr) {
        (void)hipFuncSetAttribute(
            reinterpret_cast<const void*>(gemm_bf16x3_p),
            hipFuncAttributeMaxDynamicSharedMemorySize, 147456);
        s_attr = 1;
    }

    // workspace: 3.1 (Wp) + 154.1 (Xp) + 205.5 (d) + 6.4 (spikes) = 369 MB
    char* p = (char*)d_ws;
    unsigned short* Wp = (unsigned short*)p;  p += (size_t)3 * 1024 * IN * 2;
    unsigned short* Xp = (unsigned short*)p;  p += (size_t)3 * MH * IN * 2;
    float* d1buf = (float*)p;                 p += (size_t)MH * HD * 4;
    float* d2buf = (float*)p;                 p += (size_t)MH * HD * 4;
    unsigned short* spikes = (unsigned short*)p;

    const size_t WPS = (size_t)1024 * IN;    // W plane stride (elems)
    const size_t XPS = (size_t)MH * IN;      // X plane stride (elems)

    // split W1 (plane rows 0..511) and W2 (rows 512..1023)
    split3<<<dim3(128), dim3(256), 0, stream>>>(
        W1, Wp, Wp + WPS, Wp + 2 * WPS, (long)HD * IN / 8);
    split3<<<dim3(128), dim3(256), 0, stream>>>(
        W2, Wp + (size_t)HD * IN, Wp + WPS + (size_t)HD * IN,
        Wp + 2 * WPS + (size_t)HD * IN, (long)HD * IN / 8);

    for (int half = 0; half < 2; ++half) {
        split3<<<dim3((unsigned)(((long)MH * IN / 8 + 255) / 256)), dim3(256), 0, stream>>>(
            X + (size_t)half * MH * IN, Xp, Xp + XPS, Xp + 2 * XPS, (long)MH * IN / 8);
        gemm_bf16x3_p<<<dim3(1568), dim3(512), 147456, stream>>>(
            Xp, Wp, b1, b2, d1buf, d2buf);
        scan_half<<<dim3(512), dim3(64), 0, stream>>>(
            d1buf, d2buf, tau_m, tau_n1, tau_n2, mem0, spike0,
            spikes, half * 64);
    }
    readout<<<dim3(BB * TT / 256), dim3(256), 0, stream>>>(spikes, Wr, br, out);
}

// Round 3
// 1096.350 us; speedup vs baseline: 1.0901x; 1.0901x over previous
//
#include <hip/hip_runtime.h>
#include <cmath>

#define HD 512      // hidden
#define IN 512      // input features (K)
#define TT 784      // timesteps
#define BB 128      // batch
#define MH 50176    // rows per batch-half (64 * 784)

typedef short short8 __attribute__((ext_vector_type(8)));
typedef unsigned short ushort8 __attribute__((ext_vector_type(8)));
typedef float floatx4 __attribute__((ext_vector_type(4)));

#define GLDS(gp, lp) __builtin_amdgcn_global_load_lds( \
    (const __attribute__((address_space(1))) void*)(gp), \
    (__attribute__((address_space(3))) void*)(lp), 16, 0, 0)

__device__ __forceinline__ unsigned short bf16_rne(float x) {
    unsigned u = __float_as_uint(x);
    unsigned r = u + 0x7FFFu + ((u >> 16) & 1u);
    return (unsigned short)(r >> 16);
}
__device__ __forceinline__ float bf16_f(unsigned short s) {
    return __uint_as_float(((unsigned)s) << 16);
}

// ---------------- split fp32 -> 3 bf16 planes (exact residual chain) --------
__global__ __launch_bounds__(256) void split3(
    const float* __restrict__ src, unsigned short* __restrict__ p1,
    unsigned short* __restrict__ p2, unsigned short* __restrict__ p3, long n8)
{
    long g = (long)blockIdx.x * 256 + threadIdx.x;
    if (g >= n8) return;
    const float* xp = src + g * 8;
    ushort8 o1, o2, o3;
#pragma unroll
    for (int j = 0; j < 8; ++j) {
        float x = xp[j];
        unsigned short s1 = bf16_rne(x);
        float r1 = x - bf16_f(s1);                 // exact in fp32
        unsigned short s2 = bf16_rne(r1);
        float r2 = r1 - bf16_f(s2);                // exact in fp32
        unsigned short s3 = bf16_rne(r2);
        o1[j] = s1; o2[j] = s2; o3[j] = s3;
    }
    *(ushort8*)(p1 + g * 8) = o1;
    *(ushort8*)(p2 + g * 8) = o2;
    *(ushort8*)(p3 + g * 8) = o3;
}

// ---------------- MFMA GEMM (bf16x3): d = X*W^T + bias ----------------------
// X*W ~= a1b1 + (a1b2 + a2b1) + (a1b3 + a2b2 + a3b1), fp32 accum.
// 128x128 tile, 4 waves of 64x64, 16x16x32 MFMA, K-step 32. 48 KB LDS.
// R3: XCD-chunked block swizzle — blockIdx&7 = XCD chunk, 392 blocks/chunk;
// 8 consecutive blocks in a chunk share one 393 KB A-panel (+3 MB Wp) -> the
// whole working set fits the XCD-private 4 MB L2 (R2 measured FETCH 704->166MB
// with this remap on the 256-tile variant).
__global__ __launch_bounds__(256, 2) void gemm_bf16x3(
    const unsigned short* __restrict__ Xp,   // [3][MH][512]
    const unsigned short* __restrict__ Wp,   // [3][1024][512]
    const float* __restrict__ b1, const float* __restrict__ b2,
    float* __restrict__ d1buf, float* __restrict__ d2buf)
{
    __shared__ unsigned short lds[6][128][32];   // A1,A2,A3,B1,B2,B3
    unsigned short* lflat = &lds[0][0][0];
    const int tid  = threadIdx.x;
    const int lane = tid & 63;
    const int w    = tid >> 6;
    // XCD-chunked remap: 3136 blocks = 8 chunks x 392 (bijective).
    const int wg = (blockIdx.x & 7) * 392 + (blockIdx.x >> 3);
    const int pm = wg >> 3;             // 0..391 over MH
    const int pn = wg & 7;              // 0..7 over N=1024 (fast -> A reuse)
    const int m0 = pm * 128;
    const int n0 = pn * 128;

    // 12 staging pointers per wave: seg = w*12 + j covers 48 segments of
    // 16 rows x 32 cols (1 KB); GLDS writes base + lane*16B.
    const unsigned short* gp[12];
    {
        const int rsub = lane >> 2;          // row within 16-row segment
        const int csub = (lane & 3) * 8;     // ushort offset within row
#pragma unroll
        for (int j = 0; j < 12; ++j) {
            int seg = w * 12 + j;
            int p = seg >> 3, sub = seg & 7;
            int row16 = sub * 16 + rsub;
            gp[j] = (p < 3)
              ? Xp + ((size_t)p * MH + m0 + row16) * IN + csub
              : Wp + ((size_t)(p - 3) * 1024 + n0 + row16) * IN + csub;
        }
    }

    floatx4 acc[4][4];
#pragma unroll
    for (int i = 0; i < 4; ++i)
#pragma unroll
        for (int j = 0; j < 4; ++j) acc[i][j] = (floatx4){0.f, 0.f, 0.f, 0.f};

    const int wm = w >> 1, wn = w & 1;
    const int c16 = lane & 15;
    const int q8  = (lane >> 4) * 8;

    for (int ks = 0; ks < IN; ks += 32) {
#pragma unroll
        for (int j = 0; j < 12; ++j)
            GLDS(gp[j] + ks, lflat + (size_t)(w * 12 + j) * 512);
        __syncthreads();

        short8 Bf[3][4];
#pragma unroll
        for (int p = 0; p < 3; ++p)
#pragma unroll
            for (int fj = 0; fj < 4; ++fj)
                Bf[p][fj] = *(const short8*)&lds[3 + p][wn * 64 + fj * 16 + c16][q8];

#pragma unroll
        for (int fi = 0; fi < 4; ++fi) {
            const int r = wm * 64 + fi * 16 + c16;
            short8 a1 = *(const short8*)&lds[0][r][q8];
            short8 a2 = *(const short8*)&lds[1][r][q8];
            short8 a3 = *(const short8*)&lds[2][r][q8];
#pragma unroll
            for (int fj = 0; fj < 4; ++fj) {
                floatx4 c = acc[fi][fj];
                c = __builtin_amdgcn_mfma_f32_16x16x32_bf16(a3, Bf[0][fj], c, 0, 0, 0);
                c = __builtin_amdgcn_mfma_f32_16x16x32_bf16(a2, Bf[1][fj], c, 0, 0, 0);
                c = __builtin_amdgcn_mfma_f32_16x16x32_bf16(a1, Bf[2][fj], c, 0, 0, 0);
                c = __builtin_amdgcn_mfma_f32_16x16x32_bf16(a2, Bf[0][fj], c, 0, 0, 0);
                c = __builtin_amdgcn_mfma_f32_16x16x32_bf16(a1, Bf[1][fj], c, 0, 0, 0);
                c = __builtin_amdgcn_mfma_f32_16x16x32_bf16(a1, Bf[0][fj], c, 0, 0, 0);
                acc[fi][fj] = c;
            }
        }
        __syncthreads();
    }

    // epilogue: C layout col=lane&15, row=(lane>>4)*4+reg (m89-verified)
    const int quad = lane >> 4;
    const bool first = (n0 < HD);
    const float* bias = first ? b1 : b2;
    float* obuf = first ? d1buf : d2buf;
    const int nb = n0 & (HD - 1);
    float bv[4];
#pragma unroll
    for (int fj = 0; fj < 4; ++fj) bv[fj] = bias[nb + wn * 64 + fj * 16 + c16];
#pragma unroll
    for (int fi = 0; fi < 4; ++fi) {
#pragma unroll
        for (int fj = 0; fj < 4; ++fj) {
            int n = nb + wn * 64 + fj * 16 + c16;
#pragma unroll
            for (int r = 0; r < 4; ++r) {
                int m = m0 + wm * 64 + fi * 16 + quad * 4 + r;
                obuf[(size_t)m * HD + n] = acc[fi][fj][r] + bv[fj];
            }
        }
    }
}

// ---------------- Scan: full T per (b,h), one batch-half per dispatch -------
// R3: 2-group register ping-pong prefetch. Only 2 waves/CU resident, so the
// 49 dependent load-groups were latency-bound; prefetching group g+1 while
// computing g hides one full HBM/L2 latency per group.
#define LOADG(g, A1, A2) do {                                        \
    _Pragma("unroll")                                                \
    for (int i = 0; i < 16; ++i) {                                   \
        A1[i] = p1[(size_t)((g) * 16 + i) * HD];                     \
        A2[i] = p2[(size_t)((g) * 16 + i) * HD];                     \
    } } while (0)

#define COMPG(g, A1, A2) do {                                        \
    unsigned int wq = 0;                                             \
    _Pragma("unroll")                                                \
    for (int i = 0; i < 16; ++i) {                                   \
        d1 = be1 * d1 + (1.f - be1) * A1[i];                         \
        d2 = be2 * d2 + (1.f - be2) * A2[i];                         \
        float tot = d1 + d2;                                         \
        mem = mem * alpha + (1.f - alpha) * tot - spk;               \
        bool fire = (mem - 1.0f) > 0.f;                              \
        spk = fire ? 1.f : 0.f;                                      \
        wq |= (fire ? 1u : 0u) << i;                                 \
    }                                                                \
    sp[(size_t)(g) * HD] = (unsigned short)wq; } while (0)

__global__ __launch_bounds__(64) void scan_half(
    const float* __restrict__ d1buf, const float* __restrict__ d2buf,
    const float* __restrict__ tau_m, const float* __restrict__ tau_n1,
    const float* __restrict__ tau_n2,
    const float* __restrict__ mem0, const float* __restrict__ spike0,
    unsigned short* __restrict__ spikes, int b0)
{
    const int gid = blockIdx.x * 64 + threadIdx.x;   // 0..32767
    const int h  = gid & (HD - 1);
    const int bl = gid >> 9;                          // local batch 0..63
    const int b  = b0 + bl;
    const float alpha = 1.f / (1.f + expf(-tau_m[h]));
    const float be1   = 1.f / (1.f + expf(-tau_n1[h]));
    const float be2   = 1.f / (1.f + expf(-tau_n2[h]));
    float mem = mem0[b * HD + h];
    float spk = spike0[b * HD + h];
    float d1 = 0.f, d2 = 0.f;
    const float* p1 = d1buf + (size_t)bl * TT * HD + h;
    const float* p2 = d2buf + (size_t)bl * TT * HD + h;
    unsigned short* sp = spikes + (size_t)b * (TT / 16) * HD + h;

    float a1A[16], a2A[16], a1B[16], a2B[16];
    LOADG(0, a1A, a2A);
#pragma unroll 1
    for (int g = 0; g < 48; g += 2) {       // 49 groups total (0..48)
        LOADG(g + 1, a1B, a2B);
        COMPG(g,     a1A, a2A);
        LOADG(g + 2, a1A, a2A);             // g+2 <= 48 always (g <= 46)
        COMPG(g + 1, a1B, a2B);
    }
    COMPG(48, a1A, a2A);
}

// ---------------- Readout (round-1/4 validated) -----------------------------
__global__ __launch_bounds__(256) void readout(
    const unsigned short* __restrict__ spikes,
    const float* __restrict__ Wr, const float* __restrict__ br,
    float* __restrict__ out)
{
    __shared__ float WrS[10 * HD];   // 20 KB, layout [o][h]
    __shared__ float brS[10];
    const int tid = threadIdx.x;
    for (int i = tid; i < 10 * HD; i += 256) WrS[i] = Wr[i];
    if (tid < 10) brS[tid] = br[tid];
    __syncthreads();

    const int gid = blockIdx.x * 256 + tid;      // 0..100351 = b*784+t
    const int t = gid % TT;
    const int b = gid / TT;
    const int tw  = t >> 4;
    const int bit = t & 15;
    const unsigned short* row = spikes + ((size_t)b * (TT / 16) + tw) * HD;

    float acc[10];
#pragma unroll
    for (int o = 0; o < 10; ++o) acc[o] = brS[o];

    for (int h = 0; h < HD; ++h) {
        float s = (float)((row[h] >> bit) & 1);
#pragma unroll
        for (int o = 0; o < 10; ++o) acc[o] = fmaf(s, WrS[o * HD + h], acc[o]);
    }
    float* op = out + (size_t)gid * 10;
#pragma unroll
    for (int o = 0; o < 10; ++o) op[o] = acc[o];
}

// ---------------------------------------------------------------------------
extern "C" void kernel_launch(void* const* d_in, const int* in_sizes, int n_in,
                              void* d_out, int out_size, void* d_ws, size_t ws_size,
                              hipStream_t stream)
{
    const float* X      = (const float*)d_in[0];
    const float* W1     = (const float*)d_in[1];
    const float* b1     = (const float*)d_in[2];
    const float* W2     = (const float*)d_in[3];
    const float* b2     = (const float*)d_in[4];
    const float* tau_m  = (const float*)d_in[5];
    const float* tau_n1 = (const float*)d_in[6];
    const float* tau_n2 = (const float*)d_in[7];
    const float* Wr     = (const float*)d_in[8];
    const float* br     = (const float*)d_in[9];
    const float* mem0   = (const float*)d_in[10];
    const float* spike0 = (const float*)d_in[11];
    float* out = (float*)d_out;

    // workspace: 3.1 (Wp) + 154.1 (Xp) + 205.5 (d) + 6.4 (spikes) = 369 MB
    char* p = (char*)d_ws;
    unsigned short* Wp = (unsigned short*)p;  p += (size_t)3 * 1024 * IN * 2;
    unsigned short* Xp = (unsigned short*)p;  p += (size_t)3 * MH * IN * 2;
    float* d1buf = (float*)p;                 p += (size_t)MH * HD * 4;
    float* d2buf = (float*)p;                 p += (size_t)MH * HD * 4;
    unsigned short* spikes = (unsigned short*)p;

    const size_t WPS = (size_t)1024 * IN;    // W plane stride (elems)
    const size_t XPS = (size_t)MH * IN;      // X plane stride (elems)

    // split W1 (plane rows 0..511) and W2 (rows 512..1023)
    split3<<<dim3(128), dim3(256), 0, stream>>>(
        W1, Wp, Wp + WPS, Wp + 2 * WPS, (long)HD * IN / 8);
    split3<<<dim3(128), dim3(256), 0, stream>>>(
        W2, Wp + (size_t)HD * IN, Wp + WPS + (size_t)HD * IN,
        Wp + 2 * WPS + (size_t)HD * IN, (long)HD * IN / 8);

    for (int half = 0; half < 2; ++half) {
        split3<<<dim3((unsigned)(((long)MH * IN / 8 + 255) / 256)), dim3(256), 0, stream>>>(
            X + (size_t)half * MH * IN, Xp, Xp + XPS, Xp + 2 * XPS, (long)MH * IN / 8);
        gemm_bf16x3<<<dim3(392 * 8), dim3(256), 0, stream>>>(
            Xp, Wp, b1, b2, d1buf, d2buf);
        scan_half<<<dim3(512), dim3(64), 0, stream>>>(
            d1buf, d2buf, tau_m, tau_n1, tau_n2, mem0, spike0,
            spikes, half * 64);
    }
    readout<<<dim3(BB * TT / 256), dim3(256), 0, stream>>>(spikes, Wr, br, out);
}